// Round 5
// baseline (8193.537 us; speedup 1.0000x reference)
//
#include <hip/hip_runtime.h>
#include <hip/hip_bf16.h>

// Problem sizes
#define Bb 128
#define Tt 1024
#define Dd 256
#define Hh 512
#define G4 2048
#define Oo 256

#define NBG 8       // batch groups (16 rows each), ideally one per XCD
#define WPB 8       // workgroups per batch group
#define NWG 64
#define BLOCK 512   // 8 waves

#define SPIN_CAP (1u << 22)   // escape valve: never hang the harness

typedef __attribute__((ext_vector_type(8)))  short  short8;
typedef __attribute__((ext_vector_type(4)))  float  f32x4;
typedef unsigned long long u64;

// ws layout: [xcc_post: 64 ints][cnt: 8 x 128B @256][hbuf: 2*128*512 bf16 @4096]
#define XCC_OFF  0
#define CNT_OFF  256
#define HBUF_OFF 4096
#define WS_ZERO_BYTES (4096 + Bb*Hh*2)   // xcc + counters + hbuf half 0

__device__ __forceinline__ short f2bf(float f) {
  __hip_bfloat16 h = __float2bfloat16(f);
  return *reinterpret_cast<short*>(&h);
}
__device__ __forceinline__ float sigm(float x) {
  return __builtin_amdgcn_rcpf(1.f + __expf(-x));
}
__device__ __forceinline__ float tanh_(float x) {
  return fmaf(2.f, __builtin_amdgcn_rcpf(1.f + __expf(-2.f * x)), -1.f);
}

// Raw barriers with counted waits (avoid __syncthreads' vmcnt(0) full drain).
__device__ __forceinline__ void bar_ctrl() {               // control-only
  asm volatile("s_barrier" ::: "memory");
}
__device__ __forceinline__ void bar_lds() {                // LDS handoff
  asm volatile("s_waitcnt lgkmcnt(0)\n\ts_barrier" ::: "memory");
}
__device__ __forceinline__ void bar_vm2() {                // stores drained, 2 refills in flight
  asm volatile("s_waitcnt vmcnt(2) lgkmcnt(0)\n\ts_barrier" ::: "memory");
}
__device__ __forceinline__ void bar_vm0() {                // full drain (tail steps)
  asm volatile("s_waitcnt vmcnt(0) lgkmcnt(0)\n\ts_barrier" ::: "memory");
}

#define MFMA16(A, B, C) __builtin_amdgcn_mfma_f32_16x16x32_bf16((A), (B), (C), 0, 0, 0)

__global__ __launch_bounds__(BLOCK, 2) void lstm_seq(
    const float* __restrict__ X, const float* __restrict__ Wi,
    const float* __restrict__ Wh, const float* __restrict__ bias,
    char* hbuf, int* cnts, int* xcc_post)
{
  __shared__ char sH[16 * 1024];   // slow-path h staging only
  __shared__ char sX[16 * 512];    // x tile (bf16, swizzled); slow-path h repack scratch
  __shared__ int sFast;

  const int tid  = threadIdx.x;
  const int w    = tid >> 6;      // wave 0..7
  const int lane = tid & 63;

  const int bg  = blockIdx.x & 7;  // batch group == target XCD (round-robin heur.)
  const int gjw = blockIdx.x >> 3; // col-group within bg: h-cols [gjw*64, +64)

  // ---- XCD co-residency check (one-time). Fast mode only if all 8 wgs of
  // this bg share an XCC; otherwise agent-scope fallback (always correct).
  int myxcc;
  asm volatile("s_getreg_b32 %0, hwreg(HW_REG_XCC_ID)" : "=s"(myxcc));
  if (tid == 0) {
    __hip_atomic_store(&xcc_post[blockIdx.x], myxcc + 1,
                       __ATOMIC_RELAXED, __HIP_MEMORY_SCOPE_AGENT);
    int ok = 1;
    for (int p = 0; p < WPB; ++p) {
      int v; unsigned spin = 0;
      do {
        v = __hip_atomic_load(&xcc_post[bg + p * NBG],
                              __ATOMIC_RELAXED, __HIP_MEMORY_SCOPE_AGENT);
      } while (v == 0 && ++spin < SPIN_CAP);
      ok &= (v == myxcc + 1);
    }
    sFast = ok;
  }
  __syncthreads();
  const bool fast = (sFast != 0);
  int* cnt = cnts + bg * 32;  // 128B apart per bg

  // ---- Persistent weight B-fragments: wf[nt][kk], nt0 = gates i,f ; nt1 = g,o
  // B lane map (16x16x32): col = lane&15, k = kk*32 + (lane>>4)*8 + i
  short8 wf[2][24];
  float bv[2];
#pragma unroll
  for (int nt = 0; nt < 2; ++nt) {
    int c = nt * 16 + (lane & 15);
    int gate = c >> 3, jj0 = c & 7;
    int colg = gate * Hh + gjw * 64 + w * 8 + jj0;
    bv[nt] = bias[colg];
#pragma unroll
    for (int kk = 0; kk < 24; ++kk) {
      short8 f;
#pragma unroll
      for (int i = 0; i < 8; ++i) {
        int k = kk * 32 + (lane >> 4) * 8 + i;
        float v = (k < Hh) ? Wh[(size_t)k * G4 + colg]
                           : Wi[(size_t)(k - Hh) * G4 + colg];
        f[i] = f2bf(v);
      }
      wf[nt][kk] = f;
    }
  }

  const int cjj  = lane & 15;        // MFMA col / A row
  const int kgrp = lane >> 4;        // 0..3
  const int arow = cjj;
  const int aswz = (arow & 7) << 4;
  const int hi8  = (cjj >> 3) & 1;   // 0: owns i,g ; 1: owns f,o
  const int jj   = cjj & 7;
  const int ocol = gjw * 64 + w * 8 + jj;   // h-col this lane stores
  float cpr[2] = {0.f, 0.f};         // c-state rows kgrp*4+hi8*2+{0,1}

  // ---- x prefetch (2-step pipeline in registers)
  const int xrow = tid >> 5, xseg = tid & 31;     // wg covers 16 rows x 256 f32
  const float* xbase = X + (size_t)(bg * 16 + xrow) * Tt * Dd + xseg * 8;
  f32x4 xA0 = *reinterpret_cast<const f32x4*>(xbase);
  f32x4 xA1 = *reinterpret_cast<const f32x4*>(xbase + 4);
  f32x4 xB0 = *reinterpret_cast<const f32x4*>(xbase + Dd);
  f32x4 xB1 = *reinterpret_cast<const f32x4*>(xbase + Dd + 4);

  auto STEP = [&](int s, f32x4& xv0, f32x4& xv1) {
    const char* hread = hbuf + (size_t)((s - 1) & 1) * (Bb * Hh * 2);
    char*      hwrite = hbuf + (size_t)(s & 1) * (Bb * Hh * 2);

    // 1. stage x_t into sX (from regs prefetched 2 steps ago)
    {
      short8 xb;
      xb[0] = f2bf(xv0[0]); xb[1] = f2bf(xv0[1]); xb[2] = f2bf(xv0[2]); xb[3] = f2bf(xv0[3]);
      xb[4] = f2bf(xv1[0]); xb[5] = f2bf(xv1[1]); xb[6] = f2bf(xv1[2]); xb[7] = f2bf(xv1[3]);
      *reinterpret_cast<short8*>(sX + xrow * 512 + ((xseg * 16) ^ ((xrow & 7) << 4))) = xb;
    }
    bar_lds();

    // 2. x-part MFMA (independent of h) — overlaps the poll
    f32x4 acc0, acc1;
#pragma unroll
    for (int m = 0; m < 4; ++m) { acc0[m] = bv[0]; acc1[m] = bv[1]; }
#pragma unroll
    for (int kk = 0; kk < 8; ++kk) {
      short8 a = *reinterpret_cast<const short8*>(
          sX + arow * 512 + ((kk * 64 + kgrp * 16) ^ aswz));
      acc0 = MFMA16(a, wf[0][16 + kk], acc0);
      acc1 = MFMA16(a, wf[1][16 + kk], acc1);
    }

    // 3. wait for the 8 producers of this bg (step s-1)
    if (s > 1 && tid == 0) {
      const int tgt = WPB * (s - 1);
      unsigned spin = 0;
      if (fast) {
        while ((__hip_atomic_fetch_add(cnt, 0x10000, __ATOMIC_RELAXED,
                                       __HIP_MEMORY_SCOPE_WORKGROUP) & 0xFFFF) < tgt
               && ++spin < SPIN_CAP) {}
      } else {
        while (__hip_atomic_load(cnt, __ATOMIC_RELAXED,
                                 __HIP_MEMORY_SCOPE_AGENT) < tgt
               && ++spin < SPIN_CAP) {
          __builtin_amdgcn_s_sleep(1);
        }
      }
    }
    bar_ctrl();

    // 4.+5. h-part MFMA
    if (fast) {
      asm volatile("buffer_inv sc0" ::: "memory");   // L1-only inv; fill from XCD L2
      // A-fragments straight from global (row-major bf16 h): 16B per kk
      const char* hb = hread + (size_t)(bg * 16 + arow) * (Hh * 2) + kgrp * 16;
      short8 a0, a1, a2, a3, b0, b1, b2, b3;
      a0 = *reinterpret_cast<const short8*>(hb + 0 * 64);
      a1 = *reinterpret_cast<const short8*>(hb + 1 * 64);
      a2 = *reinterpret_cast<const short8*>(hb + 2 * 64);
      a3 = *reinterpret_cast<const short8*>(hb + 3 * 64);
      b0 = *reinterpret_cast<const short8*>(hb + 4 * 64);
      b1 = *reinterpret_cast<const short8*>(hb + 5 * 64);
      b2 = *reinterpret_cast<const short8*>(hb + 6 * 64);
      b3 = *reinterpret_cast<const short8*>(hb + 7 * 64);
      acc0 = MFMA16(a0, wf[0][0], acc0); acc1 = MFMA16(a0, wf[1][0], acc1);
      acc0 = MFMA16(a1, wf[0][1], acc0); acc1 = MFMA16(a1, wf[1][1], acc1);
      acc0 = MFMA16(a2, wf[0][2], acc0); acc1 = MFMA16(a2, wf[1][2], acc1);
      acc0 = MFMA16(a3, wf[0][3], acc0); acc1 = MFMA16(a3, wf[1][3], acc1);
      a0 = *reinterpret_cast<const short8*>(hb + 8 * 64);
      a1 = *reinterpret_cast<const short8*>(hb + 9 * 64);
      a2 = *reinterpret_cast<const short8*>(hb + 10 * 64);
      a3 = *reinterpret_cast<const short8*>(hb + 11 * 64);
      acc0 = MFMA16(b0, wf[0][4], acc0); acc1 = MFMA16(b0, wf[1][4], acc1);
      acc0 = MFMA16(b1, wf[0][5], acc0); acc1 = MFMA16(b1, wf[1][5], acc1);
      acc0 = MFMA16(b2, wf[0][6], acc0); acc1 = MFMA16(b2, wf[1][6], acc1);
      acc0 = MFMA16(b3, wf[0][7], acc0); acc1 = MFMA16(b3, wf[1][7], acc1);
      b0 = *reinterpret_cast<const short8*>(hb + 12 * 64);
      b1 = *reinterpret_cast<const short8*>(hb + 13 * 64);
      b2 = *reinterpret_cast<const short8*>(hb + 14 * 64);
      b3 = *reinterpret_cast<const short8*>(hb + 15 * 64);
      acc0 = MFMA16(a0, wf[0][8],  acc0); acc1 = MFMA16(a0, wf[1][8],  acc1);
      acc0 = MFMA16(a1, wf[0][9],  acc0); acc1 = MFMA16(a1, wf[1][9],  acc1);
      acc0 = MFMA16(a2, wf[0][10], acc0); acc1 = MFMA16(a2, wf[1][10], acc1);
      acc0 = MFMA16(a3, wf[0][11], acc0); acc1 = MFMA16(a3, wf[1][11], acc1);
      acc0 = MFMA16(b0, wf[0][12], acc0); acc1 = MFMA16(b0, wf[1][12], acc1);
      acc0 = MFMA16(b1, wf[0][13], acc0); acc1 = MFMA16(b1, wf[1][13], acc1);
      acc0 = MFMA16(b2, wf[0][14], acc0); acc1 = MFMA16(b2, wf[1][14], acc1);
      acc0 = MFMA16(b3, wf[0][15], acc0); acc1 = MFMA16(b3, wf[1][15], acc1);
    } else {
      // fallback: agent-scope loads -> sH -> ds_read (always correct)
#pragma unroll
      for (int q = 0; q < 2; ++q) {
        int c = tid + q * 512, row = c >> 6, off = c & 63;
        const u64* src = reinterpret_cast<const u64*>(
            hread + (size_t)(bg * 16 + row) * 1024 + off * 16);
        u64 lo = __hip_atomic_load(src,     __ATOMIC_RELAXED, __HIP_MEMORY_SCOPE_AGENT);
        u64 hi = __hip_atomic_load(src + 1, __ATOMIC_RELAXED, __HIP_MEMORY_SCOPE_AGENT);
        union { u64 u[2]; f32x4 v; } cv; cv.u[0] = lo; cv.u[1] = hi;
        *reinterpret_cast<f32x4*>(sH + row * 1024 + ((off * 16) ^ ((row & 7) << 4))) = cv.v;
      }
      bar_lds();
#pragma unroll
      for (int kk = 0; kk < 16; ++kk) {
        short8 a = *reinterpret_cast<const short8*>(
            sH + arow * 1024 + ((kk * 64 + kgrp * 16) ^ aswz));
        acc0 = MFMA16(a, wf[0][kk], acc0);
        acc1 = MFMA16(a, wf[1][kk], acc1);
      }
    }

    // 6. in-register epilogue: pairs (lane, lane^8) swap i/f and g/o
    float o0[4], o1[4];
#pragma unroll
    for (int m = 0; m < 4; ++m) {
      o0[m] = __shfl_xor(acc0[m], 8);
      o1[m] = __shfl_xor(acc1[m], 8);
    }
    float hv[2];
#pragma unroll
    for (int q = 0; q < 2; ++q) {
      int m = hi8 * 2 + q;
      float iv = hi8 ? o0[m]   : acc0[m];
      float fv = hi8 ? acc0[m] : o0[m];
      float gv = hi8 ? o1[m]   : acc1[m];
      float ov = hi8 ? acc1[m] : o1[m];
      float ig = sigm(iv), fg = sigm(fv), gg = tanh_(gv), og = sigm(ov);
      float c = fg * cpr[q] + ig * gg;
      cpr[q] = c;
      hv[q] = og * tanh_(c);
    }
    const int orow = kgrp * 4 + hi8 * 2;   // this lane's 2 rows: orow, orow+1

    if (fast) {
      __hip_bfloat16* hw = reinterpret_cast<__hip_bfloat16*>(hwrite)
                           + (size_t)(bg * 16 + orow) * Hh + ocol;
      hw[0]  = __float2bfloat16(hv[0]);
      hw[Hh] = __float2bfloat16(hv[1]);
    } else {
      unsigned short* hs = reinterpret_cast<unsigned short*>(sX);  // sX free now
      __hip_bfloat16 h0 = __float2bfloat16(hv[0]), h1 = __float2bfloat16(hv[1]);
      hs[orow * 72 + w * 8 + jj]       = *reinterpret_cast<unsigned short*>(&h0);
      hs[(orow + 1) * 72 + w * 8 + jj] = *reinterpret_cast<unsigned short*>(&h1);
      bar_lds();
      if (tid < 128) {
        int row = tid >> 3, colq = tid & 7;
        union { f32x4 v; u64 u[2]; } cv;
        cv.v = *reinterpret_cast<const f32x4*>(
            reinterpret_cast<const char*>(hs) + row * 144 + colq * 16);
        u64* d64 = reinterpret_cast<u64*>(
            hwrite + ((size_t)(bg * 16 + row) * Hh + gjw * 64 + colq * 8) * 2);
        __hip_atomic_store(d64,     cv.u[0], __ATOMIC_RELAXED, __HIP_MEMORY_SCOPE_AGENT);
        __hip_atomic_store(d64 + 1, cv.u[1], __ATOMIC_RELAXED, __HIP_MEMORY_SCOPE_AGENT);
      }
    }

    // 7. refill x (for step s+2) AFTER stores; counted-wait barrier keeps the
    // refills in flight (in-order vmcnt retirement => older stores drained).
    if (s + 2 <= Tt) {
      xv0 = *reinterpret_cast<const f32x4*>(xbase + (size_t)(s + 1) * Dd);
      xv1 = *reinterpret_cast<const f32x4*>(xbase + (size_t)(s + 1) * Dd + 4);
      bar_vm2();
    } else {
      bar_vm0();
    }

    // 8. signal (fire-and-forget add)
    if (tid == 0) {
      if (fast) (void)__hip_atomic_fetch_add(cnt, 1, __ATOMIC_RELAXED,
                                             __HIP_MEMORY_SCOPE_WORKGROUP);
      else      (void)__hip_atomic_fetch_add(cnt, 1, __ATOMIC_RELAXED,
                                             __HIP_MEMORY_SCOPE_AGENT);
    }
  };

  for (int s = 1; s <= Tt; s += 2) {
    STEP(s,     xA0, xA1);
    STEP(s + 1, xB0, xB1);
  }
}

__global__ void out_dense(const __hip_bfloat16* __restrict__ hT,
                          const float* __restrict__ Wd,
                          const float* __restrict__ bd,
                          float* __restrict__ out)
{
  // lstm_seq's end-of-kernel release writes dirty L2 back; plain loads ok.
  __shared__ float hrow[Hh];
  int b = blockIdx.x;
  int o = threadIdx.x;
  for (int k = o; k < Hh; k += Oo)
    hrow[k] = __bfloat162float(hT[(size_t)b * Hh + k]);
  __syncthreads();
  float acc = bd[o];
  for (int k = 0; k < Hh; ++k)
    acc = fmaf(hrow[k], Wd[(size_t)k * Oo + o], acc);
  out[(size_t)b * Oo + o] = acc;
}

extern "C" void kernel_launch(void* const* d_in, const int* in_sizes, int n_in,
                              void* d_out, int out_size, void* d_ws, size_t ws_size,
                              hipStream_t stream) {
  (void)in_sizes; (void)n_in; (void)out_size; (void)ws_size;
  const float* X  = (const float*)d_in[0];
  const float* Wi = (const float*)d_in[1];
  const float* Wh = (const float*)d_in[2];
  const float* b  = (const float*)d_in[3];
  const float* Wd = (const float*)d_in[4];
  const float* bd = (const float*)d_in[5];
  float* out = (float*)d_out;

  char* ws = (char*)d_ws;
  int* xcc_post = (int*)(ws + XCC_OFF);
  int* cnts     = (int*)(ws + CNT_OFF);
  char* hbuf    = ws + HBUF_OFF;

  // zero xcc slots, counters, and h(0) every launch (graph-replay deterministic)
  hipMemsetAsync(d_ws, 0, WS_ZERO_BYTES, stream);
  lstm_seq<<<NWG, BLOCK, 0, stream>>>(X, Wi, Wh, b, hbuf, cnts, xcc_post);
  out_dense<<<Bb, Oo, 0, stream>>>((const __hip_bfloat16*)hbuf, Wd, bd, out);
}

// Round 6
// 6321.194 us; speedup vs baseline: 1.2962x; 1.2962x over previous
//
#include <hip/hip_runtime.h>
#include <hip/hip_bf16.h>

// Problem sizes
#define Bb 128
#define Tt 1024
#define Dd 256
#define Hh 512
#define G4 2048
#define Oo 256

#define NBG 8        // batch groups (16 rows each), one per XCD by construction
#define WPB 8        // worker wgs per batch group
#define NWG_LAUNCH 128  // launch 2x needed; extras exit after ticket claim
#define BLOCK 512    // 8 waves

#define SPIN_CAP (1u << 18)   // escape valve: never hang the harness

typedef __attribute__((ext_vector_type(8))) short short8;
typedef __attribute__((ext_vector_type(4))) float f32x4;
typedef __attribute__((ext_vector_type(4))) unsigned int u32x4;
typedef unsigned long long u64;

// ws layout: [tickets: 8 x 64B @0][cnt: 8 x 128B @2048][hbuf: 2*128*512 bf16 @4096]
#define TICK_OFF 0
#define CNT_OFF  2048
#define HBUF_OFF 4096
#define WS_ZERO_BYTES (4096 + Bb*Hh*2)   // tickets + counters + hbuf half 0

__device__ __forceinline__ short f2bf(float f) {
  __hip_bfloat16 h = __float2bfloat16(f);
  return *reinterpret_cast<short*>(&h);
}
__device__ __forceinline__ float sigm(float x) {
  return __builtin_amdgcn_rcpf(1.f + __expf(-x));
}
__device__ __forceinline__ float tanh_(float x) {
  return fmaf(2.f, __builtin_amdgcn_rcpf(1.f + __expf(-2.f * x)), -1.f);
}

// Raw barriers with counted waits (avoid __syncthreads' full vmcnt(0) drain
// where not needed).
__device__ __forceinline__ void bar_ctrl() {   // control-only
  asm volatile("s_barrier" ::: "memory");
}
__device__ __forceinline__ void bar_lds() {    // LDS handoff
  asm volatile("s_waitcnt lgkmcnt(0)\n\ts_barrier" ::: "memory");
}
__device__ __forceinline__ void bar_vm0() {    // all vmem + lds drained
  asm volatile("s_waitcnt vmcnt(0) lgkmcnt(0)\n\ts_barrier" ::: "memory");
}

#define MFMA16(A, B, C) __builtin_amdgcn_mfma_f32_16x16x32_bf16((A), (B), (C), 0, 0, 0)

__global__ __launch_bounds__(BLOCK, 2) void lstm_seq(
    const float* __restrict__ X, const float* __restrict__ Wi,
    const float* __restrict__ Wh, const float* __restrict__ bias,
    char* hbuf, int* cnts, int* tickets)
{
  __shared__ char sX[16 * 512];    // x tile (bf16, XOR-swizzled)
  __shared__ int sSlot;

  const int tid  = threadIdx.x;
  const int w    = tid >> 6;      // wave 0..7
  const int lane = tid & 63;

  // ---- Role claim: all workers of bg are on XCD bg BY CONSTRUCTION.
  int myxcc;
  asm volatile("s_getreg_b32 %0, hwreg(HW_REG_XCC_ID)" : "=s"(myxcc));
  myxcc &= 7;
  if (tid == 0) {
    sSlot = __hip_atomic_fetch_add(&tickets[myxcc * 16], 1,
                                   __ATOMIC_RELAXED, __HIP_MEMORY_SCOPE_AGENT);
  }
  __syncthreads();
  const int gjw = sSlot;          // col-group: h-cols [gjw*64, +64)
  if (gjw >= WPB) return;         // surplus wg: exit (wg-uniform)
  const int bg = myxcc;           // batch group == this XCD
  int* cnt = cnts + bg * 32;      // 128B apart per bg

  // ---- Persistent weight B-fragments: wf[nt][kk], nt0 = gates i,f ; nt1 = g,o
  // B lane map (16x16x32): col = lane&15, k = kk*32 + (lane>>4)*8 + i
  short8 wf[2][24];
  float bv[2];
#pragma unroll
  for (int nt = 0; nt < 2; ++nt) {
    int c = nt * 16 + (lane & 15);
    int gate = c >> 3, jj0 = c & 7;
    int colg = gate * Hh + gjw * 64 + w * 8 + jj0;
    bv[nt] = bias[colg];
#pragma unroll
    for (int kk = 0; kk < 24; ++kk) {
      short8 f;
#pragma unroll
      for (int i = 0; i < 8; ++i) {
        int k = kk * 32 + (lane >> 4) * 8 + i;
        float v = (k < Hh) ? Wh[(size_t)k * G4 + colg]
                           : Wi[(size_t)(k - Hh) * G4 + colg];
        f[i] = f2bf(v);
      }
      wf[nt][kk] = f;
    }
  }

  const int cjj  = lane & 15;        // MFMA col / A row
  const int kgrp = lane >> 4;        // 0..3
  const int arow = cjj;
  const int aswz = (arow & 7) << 4;
  const int hi8  = (cjj >> 3) & 1;   // 0: owns i,g cols ; 1: owns f,o cols
  const int jj   = cjj & 7;
  const int orow = kgrp * 4 + hi8 * 2;  // this lane's 2 rows: orow, orow+1
  float cpr[2] = {0.f, 0.f};

  // ---- x prefetch (2-step pipeline in registers)
  const int xrow = tid >> 5, xseg = tid & 31;   // wg covers 16 rows x 256 f32
  const float* xbase = X + (size_t)(bg * 16 + xrow) * Tt * Dd + xseg * 8;
  f32x4 xA0 = *reinterpret_cast<const f32x4*>(xbase);
  f32x4 xA1 = *reinterpret_cast<const f32x4*>(xbase + 4);
  f32x4 xB0 = *reinterpret_cast<const f32x4*>(xbase + Dd);
  f32x4 xB1 = *reinterpret_cast<const f32x4*>(xbase + Dd + 4);

  auto STEP = [&](int s, f32x4& xv0, f32x4& xv1) {
    const char* hread = hbuf + (size_t)((s - 1) & 1) * (Bb * Hh * 2);
    char*      hwrite = hbuf + (size_t)(s & 1) * (Bb * Hh * 2);

    // 1. stage x_t into sX (from regs prefetched 2 steps ago)
    {
      short8 xb;
      xb[0] = f2bf(xv0[0]); xb[1] = f2bf(xv0[1]); xb[2] = f2bf(xv0[2]); xb[3] = f2bf(xv0[3]);
      xb[4] = f2bf(xv1[0]); xb[5] = f2bf(xv1[1]); xb[6] = f2bf(xv1[2]); xb[7] = f2bf(xv1[3]);
      *reinterpret_cast<short8*>(sX + xrow * 512 + ((xseg * 16) ^ ((xrow & 7) << 4))) = xb;
    }
    bar_lds();

    // 2. x-part MFMA (independent of h) — overlaps the poll
    f32x4 acc0, acc1;
#pragma unroll
    for (int m = 0; m < 4; ++m) { acc0[m] = bv[0]; acc1[m] = bv[1]; }
#pragma unroll
    for (int kk = 0; kk < 8; ++kk) {
      short8 a = *reinterpret_cast<const short8*>(
          sX + arow * 512 + ((kk * 64 + kgrp * 16) ^ aswz));
      acc0 = MFMA16(a, wf[0][16 + kk], acc0);
      acc1 = MFMA16(a, wf[1][16 + kk], acc1);
    }

    // 3. wait for the 8 producers of this bg (step s-1). Non-idempotent RMW
    // executes at the XCD L2 atomic point (same point as producer +1s).
    if (s > 1 && tid == 0) {
      const int tgt = WPB * (s - 1);
      unsigned spin = 0;
      while ((int)(__hip_atomic_fetch_add((unsigned*)cnt, 0x10000u,
                                          __ATOMIC_RELAXED,
                                          __HIP_MEMORY_SCOPE_WORKGROUP) & 0xFFFFu) < tgt
             && ++spin < SPIN_CAP) {}
    }
    bar_ctrl();

    // 4. invalidate L1 (stale h lines from step s-2), refill x for s+2,
    //    then h-part MFMA with A-fragments straight from the XCD L2.
    asm volatile("buffer_inv sc0" ::: "memory");
    if (s + 2 <= Tt) {
      xv0 = *reinterpret_cast<const f32x4*>(xbase + (size_t)(s + 1) * Dd);
      xv1 = *reinterpret_cast<const f32x4*>(xbase + (size_t)(s + 1) * Dd + 4);
    }
    {
      const char* hb = hread + (size_t)(bg * 16 + arow) * (Hh * 2) + kgrp * 16;
      short8 a0, a1, a2, a3, b0, b1, b2, b3;
      a0 = *reinterpret_cast<const short8*>(hb + 0 * 64);
      a1 = *reinterpret_cast<const short8*>(hb + 1 * 64);
      a2 = *reinterpret_cast<const short8*>(hb + 2 * 64);
      a3 = *reinterpret_cast<const short8*>(hb + 3 * 64);
      b0 = *reinterpret_cast<const short8*>(hb + 4 * 64);
      b1 = *reinterpret_cast<const short8*>(hb + 5 * 64);
      b2 = *reinterpret_cast<const short8*>(hb + 6 * 64);
      b3 = *reinterpret_cast<const short8*>(hb + 7 * 64);
      acc0 = MFMA16(a0, wf[0][0], acc0); acc1 = MFMA16(a0, wf[1][0], acc1);
      acc0 = MFMA16(a1, wf[0][1], acc0); acc1 = MFMA16(a1, wf[1][1], acc1);
      acc0 = MFMA16(a2, wf[0][2], acc0); acc1 = MFMA16(a2, wf[1][2], acc1);
      acc0 = MFMA16(a3, wf[0][3], acc0); acc1 = MFMA16(a3, wf[1][3], acc1);
      a0 = *reinterpret_cast<const short8*>(hb + 8 * 64);
      a1 = *reinterpret_cast<const short8*>(hb + 9 * 64);
      a2 = *reinterpret_cast<const short8*>(hb + 10 * 64);
      a3 = *reinterpret_cast<const short8*>(hb + 11 * 64);
      acc0 = MFMA16(b0, wf[0][4], acc0); acc1 = MFMA16(b0, wf[1][4], acc1);
      acc0 = MFMA16(b1, wf[0][5], acc0); acc1 = MFMA16(b1, wf[1][5], acc1);
      acc0 = MFMA16(b2, wf[0][6], acc0); acc1 = MFMA16(b2, wf[1][6], acc1);
      acc0 = MFMA16(b3, wf[0][7], acc0); acc1 = MFMA16(b3, wf[1][7], acc1);
      b0 = *reinterpret_cast<const short8*>(hb + 12 * 64);
      b1 = *reinterpret_cast<const short8*>(hb + 13 * 64);
      b2 = *reinterpret_cast<const short8*>(hb + 14 * 64);
      b3 = *reinterpret_cast<const short8*>(hb + 15 * 64);
      acc0 = MFMA16(a0, wf[0][8],  acc0); acc1 = MFMA16(a0, wf[1][8],  acc1);
      acc0 = MFMA16(a1, wf[0][9],  acc0); acc1 = MFMA16(a1, wf[1][9],  acc1);
      acc0 = MFMA16(a2, wf[0][10], acc0); acc1 = MFMA16(a2, wf[1][10], acc1);
      acc0 = MFMA16(a3, wf[0][11], acc0); acc1 = MFMA16(a3, wf[1][11], acc1);
      acc0 = MFMA16(b0, wf[0][12], acc0); acc1 = MFMA16(b0, wf[1][12], acc1);
      acc0 = MFMA16(b1, wf[0][13], acc0); acc1 = MFMA16(b1, wf[1][13], acc1);
      acc0 = MFMA16(b2, wf[0][14], acc0); acc1 = MFMA16(b2, wf[1][14], acc1);
      acc0 = MFMA16(b3, wf[0][15], acc0); acc1 = MFMA16(b3, wf[1][15], acc1);
    }

    // 5. in-register epilogue: pairs (lane, lane^8) swap i/f and g/o
    float o0[4], o1[4];
#pragma unroll
    for (int m = 0; m < 4; ++m) {
      o0[m] = __shfl_xor(acc0[m], 8);
      o1[m] = __shfl_xor(acc1[m], 8);
    }
    float hv[2];
#pragma unroll
    for (int q = 0; q < 2; ++q) {
      int m = hi8 * 2 + q;
      float iv = hi8 ? o0[m]   : acc0[m];
      float fv = hi8 ? acc0[m] : o0[m];
      float gv = hi8 ? o1[m]   : acc1[m];
      float ov = hi8 ? acc1[m] : o1[m];
      float ig = sigm(iv), fg = sigm(fv), gg = tanh_(gv), og = sigm(ov);
      float c = fg * cpr[q] + ig * gg;
      cpr[q] = c;
      hv[q] = og * tanh_(c);
    }

    // 6. pack 8 lanes' bf16 (cols jj=0..7 of rows orow/orow+1) into 16B via
    //    3 shfl_xor rounds; lane jj==0 stores two 16B rows (write-through L2).
    {
      __hip_bfloat16 hb0 = __float2bfloat16(hv[0]);
      __hip_bfloat16 hb1 = __float2bfloat16(hv[1]);
      unsigned p0 = (unsigned)*reinterpret_cast<unsigned short*>(&hb0);
      unsigned p1 = (unsigned)*reinterpret_cast<unsigned short*>(&hb1);
      unsigned q0 = __shfl_xor(p0, 1), q1 = __shfl_xor(p1, 1);
      unsigned lo, hi;
      lo = (jj & 1) ? q0 : p0; hi = (jj & 1) ? p0 : q0;
      p0 = (lo & 0xFFFFu) | (hi << 16);
      lo = (jj & 1) ? q1 : p1; hi = (jj & 1) ? p1 : q1;
      p1 = (lo & 0xFFFFu) | (hi << 16);
      unsigned r0 = __shfl_xor(p0, 2), r1 = __shfl_xor(p1, 2);
      unsigned a0 = (jj & 2) ? r0 : p0, a1 = (jj & 2) ? p0 : r0;
      unsigned b0 = (jj & 2) ? r1 : p1, b1 = (jj & 2) ? p1 : r1;
      unsigned s0 = __shfl_xor(a0, 4), s1 = __shfl_xor(a1, 4);
      unsigned t0 = __shfl_xor(b0, 4), t1 = __shfl_xor(b1, 4);
      u32x4 v0, v1;
      if ((jj & 4) == 0) {
        v0[0] = a0; v0[1] = a1; v0[2] = s0; v0[3] = s1;
        v1[0] = b0; v1[1] = b1; v1[2] = t0; v1[3] = t1;
      } else {
        v0[0] = s0; v0[1] = s1; v0[2] = a0; v0[3] = a1;
        v1[0] = t0; v1[1] = t1; v1[2] = b0; v1[3] = b1;
      }
      if (jj == 0) {
        char* hw = hwrite + ((size_t)(bg * 16 + orow) * Hh + gjw * 64 + w * 8) * 2;
        *reinterpret_cast<u32x4*>(hw) = v0;
        *reinterpret_cast<u32x4*>(hw + Hh * 2) = v1;
      }
    }

    // 7. drain (h stores acked at L2; refills/h-loads long done), then signal.
    bar_vm0();
    if (tid == 0) {
      (void)__hip_atomic_fetch_add(cnt, 1, __ATOMIC_RELAXED,
                                   __HIP_MEMORY_SCOPE_WORKGROUP);
    }
  };

  for (int s = 1; s <= Tt; s += 2) {
    STEP(s,     xA0, xA1);
    STEP(s + 1, xB0, xB1);
  }
}

__global__ void out_dense(const __hip_bfloat16* __restrict__ hT,
                          const float* __restrict__ Wd,
                          const float* __restrict__ bd,
                          float* __restrict__ out)
{
  // lstm_seq's end-of-kernel release writes dirty L2 back; plain loads ok.
  __shared__ float hrow[Hh];
  int b = blockIdx.x;
  int o = threadIdx.x;
  for (int k = o; k < Hh; k += Oo)
    hrow[k] = __bfloat162float(hT[(size_t)b * Hh + k]);
  __syncthreads();
  float acc = bd[o];
  for (int k = 0; k < Hh; ++k)
    acc = fmaf(hrow[k], Wd[(size_t)k * Oo + o], acc);
  out[(size_t)b * Oo + o] = acc;
}

extern "C" void kernel_launch(void* const* d_in, const int* in_sizes, int n_in,
                              void* d_out, int out_size, void* d_ws, size_t ws_size,
                              hipStream_t stream) {
  (void)in_sizes; (void)n_in; (void)out_size; (void)ws_size;
  const float* X  = (const float*)d_in[0];
  const float* Wi = (const float*)d_in[1];
  const float* Wh = (const float*)d_in[2];
  const float* b  = (const float*)d_in[3];
  const float* Wd = (const float*)d_in[4];
  const float* bd = (const float*)d_in[5];
  float* out = (float*)d_out;

  char* ws = (char*)d_ws;
  int* tickets = (int*)(ws + TICK_OFF);
  int* cnts    = (int*)(ws + CNT_OFF);
  char* hbuf   = ws + HBUF_OFF;

  // zero tickets, counters, and h(0) every launch (graph-replay deterministic)
  hipMemsetAsync(d_ws, 0, WS_ZERO_BYTES, stream);
  lstm_seq<<<NWG_LAUNCH, BLOCK, 0, stream>>>(X, Wi, Wh, b, hbuf, cnts, tickets);
  out_dense<<<Bb, Oo, 0, stream>>>((const __hip_bfloat16*)hbuf, Wd, bd, out);
}

// Round 7
// 4783.797 us; speedup vs baseline: 1.7128x; 1.3214x over previous
//
#include <hip/hip_runtime.h>
#include <hip/hip_bf16.h>

// Problem sizes
#define Bb 128
#define Tt 1024
#define Dd 256
#define Hh 512
#define G4 2048
#define Oo 256

#define NBG 8        // batch groups (16 rows each), one per XCD by construction
#define WPB 8        // worker wgs per batch group
#define NWG_LAUNCH 128  // launch 2x needed; extras exit after ticket claim
#define BLOCK 512    // 8 waves

#define SPIN_CAP (1u << 18)   // escape valve: never hang the harness

typedef __attribute__((ext_vector_type(8))) short short8;
typedef __attribute__((ext_vector_type(4))) float f32x4;
typedef unsigned long long u64;

// ws layout: [tickets: 8 x 64B @0][cnt: 8 x 128B @2048][hbuf: 2*128*512 bf16 @4096]
#define TICK_OFF 0
#define CNT_OFF  2048
#define HBUF_OFF 4096
#define WS_ZERO_BYTES (4096 + Bb*Hh*2)   // tickets + counters + hbuf half 0

__device__ __forceinline__ short f2bf(float f) {
  __hip_bfloat16 h = __float2bfloat16(f);
  return *reinterpret_cast<short*>(&h);
}
__device__ __forceinline__ float sigm(float x) {
  return __builtin_amdgcn_rcpf(1.f + __expf(-x));
}
__device__ __forceinline__ float tanh_(float x) {
  return fmaf(2.f, __builtin_amdgcn_rcpf(1.f + __expf(-2.f * x)), -1.f);
}

// Raw barriers with counted waits (avoid full vmcnt(0) drains where not needed).
__device__ __forceinline__ void bar_ctrl() {   // control-only
  asm volatile("s_barrier" ::: "memory");
}
__device__ __forceinline__ void bar_lds() {    // LDS handoff
  asm volatile("s_waitcnt lgkmcnt(0)\n\ts_barrier" ::: "memory");
}
__device__ __forceinline__ void bar_vm2() {    // h-stores drained; 2 x-refills in flight
  asm volatile("s_waitcnt vmcnt(2) lgkmcnt(0)\n\ts_barrier" ::: "memory");
}
__device__ __forceinline__ void bar_vm0() {    // full drain (tail steps)
  asm volatile("s_waitcnt vmcnt(0) lgkmcnt(0)\n\ts_barrier" ::: "memory");
}

#define MFMA16(A, B, C) __builtin_amdgcn_mfma_f32_16x16x32_bf16((A), (B), (C), 0, 0, 0)

__global__ __launch_bounds__(BLOCK, 2) void lstm_seq(
    const float* __restrict__ X, const float* __restrict__ Wi,
    const float* __restrict__ Wh, const float* __restrict__ bias,
    char* hbuf, int* cnts, int* tickets)
{
  __shared__ char sH[16 * 1024];            // h tile (bf16, XOR-swizzled)
  __shared__ char sX[16 * 512];             // x tile (bf16, XOR-swizzled)
  __shared__ unsigned short hstage[16][72]; // h-slice pack buffer (padded)
  __shared__ int sSlot;

  const int tid  = threadIdx.x;
  const int w    = tid >> 6;      // wave 0..7
  const int lane = tid & 63;

  // ---- Role claim: all workers of bg are on XCD bg BY CONSTRUCTION.
  int myxcc;
  asm volatile("s_getreg_b32 %0, hwreg(HW_REG_XCC_ID)" : "=s"(myxcc));
  myxcc &= 7;
  if (tid == 0) {
    sSlot = __hip_atomic_fetch_add(&tickets[myxcc * 16], 1,
                                   __ATOMIC_RELAXED, __HIP_MEMORY_SCOPE_AGENT);
  }
  __syncthreads();
  const int gjw = sSlot;          // col-group: h-cols [gjw*64, +64)
  if (gjw >= WPB) return;         // surplus wg: exit (wg-uniform)
  const int bg = myxcc;           // batch group == this XCD
  int* cnt = cnts + bg * 32;      // 128B apart per bg

  // ---- Persistent weight B-fragments: wf[nt][kk], nt0 = gates i,f ; nt1 = g,o
  // B lane map (16x16x32): col = lane&15, k = kk*32 + (lane>>4)*8 + i
  short8 wf[2][24];
  float bv[2];
#pragma unroll
  for (int nt = 0; nt < 2; ++nt) {
    int c = nt * 16 + (lane & 15);
    int gate = c >> 3, jj0 = c & 7;
    int colg = gate * Hh + gjw * 64 + w * 8 + jj0;
    bv[nt] = bias[colg];
#pragma unroll
    for (int kk = 0; kk < 24; ++kk) {
      short8 f;
#pragma unroll
      for (int i = 0; i < 8; ++i) {
        int k = kk * 32 + (lane >> 4) * 8 + i;
        float v = (k < Hh) ? Wh[(size_t)k * G4 + colg]
                           : Wi[(size_t)(k - Hh) * G4 + colg];
        f[i] = f2bf(v);
      }
      wf[nt][kk] = f;
    }
  }

  const int cjj  = lane & 15;        // MFMA col / A row
  const int kgrp = lane >> 4;        // 0..3
  const int arow = cjj;
  const int aswz = (arow & 7) << 4;
  const int hi8  = (cjj >> 3) & 1;   // 0: owns i,g cols ; 1: owns f,o cols
  const int jj   = cjj & 7;
  const int orow = kgrp * 4 + hi8 * 2;  // this lane's 2 rows: orow, orow+1
  float cpr[2] = {0.f, 0.f};

  // ---- x prefetch (2-step pipeline in registers)
  const int xrow = tid >> 5, xseg = tid & 31;   // wg covers 16 rows x 256 f32
  const float* xbase = X + (size_t)(bg * 16 + xrow) * Tt * Dd + xseg * 8;
  f32x4 xA0 = *reinterpret_cast<const f32x4*>(xbase);
  f32x4 xA1 = *reinterpret_cast<const f32x4*>(xbase + 4);
  f32x4 xB0 = *reinterpret_cast<const f32x4*>(xbase + Dd);
  f32x4 xB1 = *reinterpret_cast<const f32x4*>(xbase + Dd + 4);

  auto STEP = [&](int s, f32x4& xv0, f32x4& xv1) {
    const char* hread = hbuf + (size_t)((s - 1) & 1) * (Bb * Hh * 2);
    char*      hwrite = hbuf + (size_t)(s & 1) * (Bb * Hh * 2);

    // 1. stage x_t into sX (from regs prefetched 2 steps ago)
    {
      short8 xb;
      xb[0] = f2bf(xv0[0]); xb[1] = f2bf(xv0[1]); xb[2] = f2bf(xv0[2]); xb[3] = f2bf(xv0[3]);
      xb[4] = f2bf(xv1[0]); xb[5] = f2bf(xv1[1]); xb[6] = f2bf(xv1[2]); xb[7] = f2bf(xv1[3]);
      *reinterpret_cast<short8*>(sX + xrow * 512 + ((xseg * 16) ^ ((xrow & 7) << 4))) = xb;
    }
    bar_lds();

    // 2. x-part MFMA (independent of h) — overlaps the poll
    f32x4 acc0, acc1;
#pragma unroll
    for (int m = 0; m < 4; ++m) { acc0[m] = bv[0]; acc1[m] = bv[1]; }
#pragma unroll
    for (int kk = 0; kk < 8; ++kk) {
      short8 a = *reinterpret_cast<const short8*>(
          sX + arow * 512 + ((kk * 64 + kgrp * 16) ^ aswz));
      acc0 = MFMA16(a, wf[0][16 + kk], acc0);
      acc1 = MFMA16(a, wf[1][16 + kk], acc1);
    }

    // 3. wait for the 8 producers of this bg (step s-1). Non-idempotent RMW
    // executes at the XCD L2 atomic point (same point as producer +1s).
    if (s > 1 && tid == 0) {
      const int tgt = WPB * (s - 1);
      unsigned spin = 0;
      while ((int)(__hip_atomic_fetch_add((unsigned*)cnt, 0x10000u,
                                          __ATOMIC_RELAXED,
                                          __HIP_MEMORY_SCOPE_WORKGROUP) & 0xFFFFu) < tgt
             && ++spin < SPIN_CAP) {}
    }
    bar_ctrl();

    // 4. invalidate L1 (stale h lines from step s-2), then cooperative
    //    coalesced h(s-1) staging: 16 rows x 512 bf16 = 16KB from XCD L2.
    asm volatile("buffer_inv sc0" ::: "memory");
#pragma unroll
    for (int q = 0; q < 2; ++q) {
      int c = tid + q * 512, row = c >> 6, off = c & 63;
      f32x4 v = *reinterpret_cast<const f32x4*>(
          hread + (size_t)(bg * 16 + row) * 1024 + off * 16);
      *reinterpret_cast<f32x4*>(sH + row * 1024 + ((off * 16) ^ ((row & 7) << 4))) = v;
    }
    bar_lds();

    // 5. h-part MFMA from LDS (swizzled, conflict-free ds_read_b128)
#pragma unroll
    for (int kk = 0; kk < 16; ++kk) {
      short8 a = *reinterpret_cast<const short8*>(
          sH + arow * 1024 + ((kk * 64 + kgrp * 16) ^ aswz));
      acc0 = MFMA16(a, wf[0][kk], acc0);
      acc1 = MFMA16(a, wf[1][kk], acc1);
    }

    // 6. in-register epilogue: pairs (lane, lane^8) swap i/f and g/o
    float o0[4], o1[4];
#pragma unroll
    for (int m = 0; m < 4; ++m) {
      o0[m] = __shfl_xor(acc0[m], 8);
      o1[m] = __shfl_xor(acc1[m], 8);
    }
    float hv[2];
#pragma unroll
    for (int q = 0; q < 2; ++q) {
      int m = hi8 * 2 + q;
      float iv = hi8 ? o0[m]   : acc0[m];
      float fv = hi8 ? acc0[m] : o0[m];
      float gv = hi8 ? o1[m]   : acc1[m];
      float ov = hi8 ? acc1[m] : o1[m];
      float ig = sigm(iv), fg = sigm(fv), gg = tanh_(gv), og = sigm(ov);
      float c = fg * cpr[q] + ig * gg;
      cpr[q] = c;
      hv[q] = og * tanh_(c);
    }

    // 7. pack h-slice in LDS, then full-line coalesced stores (128 thr x 16B)
    {
      __hip_bfloat16 h0 = __float2bfloat16(hv[0]), h1 = __float2bfloat16(hv[1]);
      hstage[orow][w * 8 + jj]     = *reinterpret_cast<unsigned short*>(&h0);
      hstage[orow + 1][w * 8 + jj] = *reinterpret_cast<unsigned short*>(&h1);
    }
    bar_lds();
    if (tid < 128) {
      int row = tid >> 3, chunk = tid & 7;
      f32x4 v = *reinterpret_cast<const f32x4*>(
          reinterpret_cast<const char*>(&hstage[0][0]) + row * 144 + chunk * 16);
      *reinterpret_cast<f32x4*>(
          hwrite + ((size_t)(bg * 16 + row) * Hh + gjw * 64 + chunk * 8) * 2) = v;
    }
    __builtin_amdgcn_sched_barrier(0);  // keep refills YOUNGER than h stores

    // 8. refill x for step s+2 (stays in flight across the barrier), signal.
    if (s + 2 <= Tt) {
      xv0 = *reinterpret_cast<const f32x4*>(xbase + (size_t)(s + 1) * Dd);
      xv1 = *reinterpret_cast<const f32x4*>(xbase + (size_t)(s + 1) * Dd + 4);
      bar_vm2();   // in-order retirement: h stores (older) fully drained
    } else {
      bar_vm0();
    }
    if (tid == 0) {
      (void)__hip_atomic_fetch_add(cnt, 1, __ATOMIC_RELAXED,
                                   __HIP_MEMORY_SCOPE_WORKGROUP);
    }
  };

  for (int s = 1; s <= Tt; s += 2) {
    STEP(s,     xA0, xA1);
    STEP(s + 1, xB0, xB1);
  }
}

__global__ void out_dense(const __hip_bfloat16* __restrict__ hT,
                          const float* __restrict__ Wd,
                          const float* __restrict__ bd,
                          float* __restrict__ out)
{
  // lstm_seq's end-of-kernel release writes dirty L2 back; plain loads ok.
  __shared__ float hrow[Hh];
  int b = blockIdx.x;
  int o = threadIdx.x;
  for (int k = o; k < Hh; k += Oo)
    hrow[k] = __bfloat162float(hT[(size_t)b * Hh + k]);
  __syncthreads();
  float acc = bd[o];
  for (int k = 0; k < Hh; ++k)
    acc = fmaf(hrow[k], Wd[(size_t)k * Oo + o], acc);
  out[(size_t)b * Oo + o] = acc;
}

extern "C" void kernel_launch(void* const* d_in, const int* in_sizes, int n_in,
                              void* d_out, int out_size, void* d_ws, size_t ws_size,
                              hipStream_t stream) {
  (void)in_sizes; (void)n_in; (void)out_size; (void)ws_size;
  const float* X  = (const float*)d_in[0];
  const float* Wi = (const float*)d_in[1];
  const float* Wh = (const float*)d_in[2];
  const float* b  = (const float*)d_in[3];
  const float* Wd = (const float*)d_in[4];
  const float* bd = (const float*)d_in[5];
  float* out = (float*)d_out;

  char* ws = (char*)d_ws;
  int* tickets = (int*)(ws + TICK_OFF);
  int* cnts    = (int*)(ws + CNT_OFF);
  char* hbuf   = ws + HBUF_OFF;

  // zero tickets, counters, and h(0) every launch (graph-replay deterministic)
  hipMemsetAsync(d_ws, 0, WS_ZERO_BYTES, stream);
  lstm_seq<<<NWG_LAUNCH, BLOCK, 0, stream>>>(X, Wi, Wh, b, hbuf, cnts, tickets);
  out_dense<<<Bb, Oo, 0, stream>>>((const __hip_bfloat16*)hbuf, Wd, bd, out);
}

// Round 8
// 2753.294 us; speedup vs baseline: 2.9759x; 1.7375x over previous
//
#include <hip/hip_runtime.h>
#include <hip/hip_bf16.h>

// Problem sizes
#define Bb 128
#define Tt 1024
#define Dd 256
#define Hh 512
#define G4 2048
#define Oo 256

#define NBG 8        // batch groups (16 rows each), one per XCD by construction
#define WPB 8        // worker wgs per batch group
#define NWG_LAUNCH 128  // launch 2x needed; surplus wgs exit after ticket claim
#define BLOCK 512    // 8 waves

#define SPIN_CAP (1u << 20)   // escape valve: never hang the harness

typedef __attribute__((ext_vector_type(8))) short short8;
typedef __attribute__((ext_vector_type(4))) float f32x4;
typedef unsigned long long u64;

// ws layout: [tickets: 8 x 64B @0][cnt: 8 x 128B @2048][hbuf: 2*128*512 bf16 @4096]
#define TICK_OFF 0
#define CNT_OFF  2048
#define HBUF_OFF 4096
#define WS_ZERO_BYTES (4096 + Bb*Hh*2)   // tickets + counters + hbuf half 0

__device__ __forceinline__ short f2bf(float f) {
  __hip_bfloat16 h = __float2bfloat16(f);
  return *reinterpret_cast<short*>(&h);
}
__device__ __forceinline__ float sigm(float x) {
  return __builtin_amdgcn_rcpf(1.f + __expf(-x));
}
__device__ __forceinline__ float tanh_(float x) {
  return fmaf(2.f, __builtin_amdgcn_rcpf(1.f + __expf(-2.f * x)), -1.f);
}

#define MFMA16(A, B, C) __builtin_amdgcn_mfma_f32_16x16x32_bf16((A), (B), (C), 0, 0, 0)

__global__ __launch_bounds__(BLOCK, 2) void lstm_seq(
    const float* __restrict__ X, const float* __restrict__ Wi,
    const float* __restrict__ Wh, const float* __restrict__ bias,
    char* hbuf, int* cnts, int* tickets)
{
  __shared__ char sH[16 * 1024];            // h tile (bf16, XOR-swizzled)
  __shared__ char sX[16 * 512];             // x tile (bf16, XOR-swizzled)
  __shared__ float sY[8][16][33];           // per-wave y staging, padded
  __shared__ unsigned short hstage[16][72]; // wg h-slice pack buffer (padded)
  __shared__ int sSlot;

  const int tid  = threadIdx.x;
  const int w    = tid >> 6;      // wave 0..7
  const int lane = tid & 63;

  // ---- Role claim: all 8 workers of a bg are on XCD bg BY CONSTRUCTION.
  int myxcc;
  asm volatile("s_getreg_b32 %0, hwreg(HW_REG_XCC_ID)" : "=s"(myxcc));
  myxcc &= 7;
  if (tid == 0) {
    sSlot = __hip_atomic_fetch_add(&tickets[myxcc * 16], 1,
                                   __ATOMIC_RELAXED, __HIP_MEMORY_SCOPE_AGENT);
  }
  __syncthreads();
  const int gjw = sSlot;          // col-group: h-cols [gjw*64, +64)
  if (gjw >= WPB) return;         // surplus wg: exit (wg-uniform)
  const int bg = myxcc;           // batch group == this XCD
  int* cnt = cnts + bg * 32;      // 128B apart per bg

  // ---- Persistent weight B-fragments: wf[nt][kk], nt0 = gates i,f ; nt1 = g,o
  // B lane map (16x16x32): col = lane&15, k = kk*32 + (lane>>4)*8 + i
  short8 wf[2][24];
  float bv[2];
#pragma unroll
  for (int nt = 0; nt < 2; ++nt) {
    int c = nt * 16 + (lane & 15);
    int gate = c >> 3, jj0 = c & 7;
    int colg = gate * Hh + gjw * 64 + w * 8 + jj0;
    bv[nt] = bias[colg];
#pragma unroll
    for (int kk = 0; kk < 24; ++kk) {
      short8 f;
#pragma unroll
      for (int i = 0; i < 8; ++i) {
        int k = kk * 32 + (lane >> 4) * 8 + i;
        float v = (k < Hh) ? Wh[(size_t)k * G4 + colg]
                           : Wi[(size_t)(k - Hh) * G4 + colg];
        f[i] = f2bf(v);
      }
      wf[nt][kk] = f;
    }
  }

  // epilogue lane mapping: lane owns rows (er0, er0+8) x h-col ejj
  const int ejj = lane & 7;
  const int er0 = lane >> 3;        // 0..7
  float cpr[2] = {0.f, 0.f};

  const int arow = lane & 15;       // MFMA A row
  const int kgrp = lane >> 4;       // 0..3
  const int aswz = (arow & 7) << 4;

  for (int s = 1; s <= Tt; ++s) {
    const char* hread  = hbuf + (size_t)((s - 1) & 1) * (Bb * Hh * 2);
    char*       hwrite = hbuf + (size_t)(s & 1) * (Bb * Hh * 2);

    // ---- stage x_t (plain cached loads, issued before the poll so their
    // latency overlaps the producer wait): 16 rows x 256 f32
    {
      int row = tid >> 5, seg = tid & 31;
      const float* xp = X + ((size_t)(bg * 16 + row) * Tt + (s - 1)) * Dd + seg * 8;
      f32x4 x0 = *reinterpret_cast<const f32x4*>(xp);
      f32x4 x1 = *reinterpret_cast<const f32x4*>(xp + 4);
      short8 xb;
      xb[0] = f2bf(x0[0]); xb[1] = f2bf(x0[1]); xb[2] = f2bf(x0[2]); xb[3] = f2bf(x0[3]);
      xb[4] = f2bf(x1[0]); xb[5] = f2bf(x1[1]); xb[6] = f2bf(x1[2]); xb[7] = f2bf(x1[3]);
      *reinterpret_cast<short8*>(sX + row * 512 + ((seg * 16) ^ ((row & 7) << 4))) = xb;
    }

    // ---- wait for the 8 producers of this bg (step s-1). Non-idempotent RMW
    // executes at the XCD L2 atomic point (same point as producer +1s).
    if (s > 1 && tid == 0) {
      const int tgt = WPB * (s - 1);
      unsigned spin = 0;
      while ((int)(__hip_atomic_fetch_add((unsigned*)cnt, 0x10000u,
                                          __ATOMIC_RELAXED,
                                          __HIP_MEMORY_SCOPE_WORKGROUP) & 0xFFFFu) < tgt
             && ++spin < SPIN_CAP) {}
    }
    __syncthreads();

    // ---- invalidate L1 (stale h lines from step s-2), cooperative coalesced
    // h(s-1) staging: 16 rows x 512 bf16 = 16KB from the shared XCD L2.
    asm volatile("buffer_inv sc0" ::: "memory");
#pragma unroll
    for (int q = 0; q < 2; ++q) {
      int c = tid + q * 512, row = c >> 6, off = c & 63;
      f32x4 v = *reinterpret_cast<const f32x4*>(
          hread + (size_t)(bg * 16 + row) * 1024 + off * 16);
      *reinterpret_cast<f32x4*>(sH + row * 1024 + ((off * 16) ^ ((row & 7) << 4))) = v;
    }
    __syncthreads();

    // ---- MFMA: 24 k-steps x 2 n-tiles of 16x16x32
    f32x4 acc0, acc1;
#pragma unroll
    for (int m = 0; m < 4; ++m) { acc0[m] = bv[0]; acc1[m] = bv[1]; }
#pragma unroll
    for (int kk = 0; kk < 16; ++kk) {   // h part, k = 0..511
      short8 a = *reinterpret_cast<const short8*>(
          sH + arow * 1024 + ((kk * 64 + kgrp * 16) ^ aswz));
      acc0 = MFMA16(a, wf[0][kk], acc0);
      acc1 = MFMA16(a, wf[1][kk], acc1);
    }
#pragma unroll
    for (int kk = 0; kk < 8; ++kk) {    // x part, k = 512..767
      short8 a = *reinterpret_cast<const short8*>(
          sX + arow * 512 + ((kk * 64 + kgrp * 16) ^ aswz));
      acc0 = MFMA16(a, wf[0][16 + kk], acc0);
      acc1 = MFMA16(a, wf[1][16 + kk], acc1);
    }

    // ---- epilogue (wave-local sY; C/D: col=lane&15, row=(lane>>4)*4+m)
    float* sYw = &sY[w][0][0];
#pragma unroll
    for (int m = 0; m < 4; ++m) {
      int row = kgrp * 4 + m;
      sYw[row * 33 + (lane & 15)]      = acc0[m];
      sYw[row * 33 + 16 + (lane & 15)] = acc1[m];
    }
#pragma unroll
    for (int q = 0; q < 2; ++q) {
      int r = er0 + q * 8;
      float yi = sYw[r * 33 + ejj];
      float yf = sYw[r * 33 + 8 + ejj];
      float yg = sYw[r * 33 + 16 + ejj];
      float yo = sYw[r * 33 + 24 + ejj];
      float ig = sigm(yi), fg = sigm(yf), gg = tanh_(yg), og = sigm(yo);
      float c = fg * cpr[q] + ig * gg;
      cpr[q] = c;
      float hh = og * tanh_(c);
      __hip_bfloat16 hb = __float2bfloat16(hh);
      hstage[r][w * 8 + ejj] = *reinterpret_cast<unsigned short*>(&hb);
    }
    __syncthreads();

    // ---- store h slice: 16 rows x 64 cols x 2B (128 threads x 16B, coalesced;
    // write-through L1 -> shared XCD L2)
    if (tid < 128) {
      int row = tid >> 3, colq = tid & 7;
      f32x4 v = *reinterpret_cast<const f32x4*>(
          reinterpret_cast<const char*>(&hstage[0][0]) + row * 144 + colq * 16);
      *reinterpret_cast<f32x4*>(
          hwrite + ((size_t)(bg * 16 + row) * Hh + gjw * 64 + colq * 8) * 2) = v;
    }
    __syncthreads();  // drains vmcnt per wave => stores complete at L2

    if (tid == 0) {
      (void)__hip_atomic_fetch_add(cnt, 1, __ATOMIC_RELAXED,
                                   __HIP_MEMORY_SCOPE_WORKGROUP);
    }
  }
}

__global__ void out_dense(const __hip_bfloat16* __restrict__ hT,
                          const float* __restrict__ Wd,
                          const float* __restrict__ bd,
                          float* __restrict__ out)
{
  // lstm_seq's end-of-kernel release writes dirty L2 back; plain loads ok.
  __shared__ float hrow[Hh];
  int b = blockIdx.x;
  int o = threadIdx.x;
  for (int k = o; k < Hh; k += Oo)
    hrow[k] = __bfloat162float(hT[(size_t)b * Hh + k]);
  __syncthreads();
  float acc = bd[o];
  for (int k = 0; k < Hh; ++k)
    acc = fmaf(hrow[k], Wd[(size_t)k * Oo + o], acc);
  out[(size_t)b * Oo + o] = acc;
}

extern "C" void kernel_launch(void* const* d_in, const int* in_sizes, int n_in,
                              void* d_out, int out_size, void* d_ws, size_t ws_size,
                              hipStream_t stream) {
  (void)in_sizes; (void)n_in; (void)out_size; (void)ws_size;
  const float* X  = (const float*)d_in[0];
  const float* Wi = (const float*)d_in[1];
  const float* Wh = (const float*)d_in[2];
  const float* b  = (const float*)d_in[3];
  const float* Wd = (const float*)d_in[4];
  const float* bd = (const float*)d_in[5];
  float* out = (float*)d_out;

  char* ws = (char*)d_ws;
  int* tickets = (int*)(ws + TICK_OFF);
  int* cnts    = (int*)(ws + CNT_OFF);
  char* hbuf   = ws + HBUF_OFF;

  // zero tickets, counters, and h(0) every launch (graph-replay deterministic)
  hipMemsetAsync(d_ws, 0, WS_ZERO_BYTES, stream);
  lstm_seq<<<NWG_LAUNCH, BLOCK, 0, stream>>>(X, Wi, Wh, b, hbuf, cnts, tickets);
  out_dense<<<Bb, Oo, 0, stream>>>((const __hip_bfloat16*)hbuf, Wd, bd, out);
}